// Round 1
// baseline (167.780 us; speedup 1.0000x reference)
//
#include <hip/hip_runtime.h>
#include <math.h>

#define HW 512
#define NIMG 24              // 8*3 images per tensor
#define NB 362               // radial bins
#define PLANE (HW*HW)
#define NC 257               // spectral columns kept (0..256), Hermitian half
#define NG 65                // col-groups per image (4 cols each; cg64 ragged)
#define NPB (NIMG*NG)        // 1560 partial-bin blocks
#define CPC 131584           // floats per component per image: 257 cols * 512

// Column storage (R14): element at row r of column c lives at
//   comp_base + img*CPC + c*512 + (r&63)*8 + (r>>6)
// i.e. pre-transposed into the col-FFT's register order: colfft lane l
// reads regs j=0..7 as one contiguous 32B chunk at c*512 + l*8.

// ws layout (float units):
#define OFF_PM  0                          // [NPB*NB] partial mag sums
#define OFF_PD  (NPB*NB)                   // [NPB*NB] partial d sums
#define OFF_PR  (2*NPB*NB)                 // P real
#define OFF_PIm (OFF_PR + NIMG*CPC)        // P imag
#define OFF_TR  (OFF_PR + 2*NIMG*CPC)      // T real
#define OFF_TI  (OFF_PR + 3*NIMG*CPC)      // T imag
#define OFF_RM  (OFF_PR + 4*NIMG*CPC)      // [NIMG*NB] reduced mag sums
#define OFF_RD  (OFF_RM + NIMG*NB)         // [NIMG*NB] reduced d sums
// total ~55.1 MiB (shrunk vs R13's 55.7)

// Exact bin for ODD integer u,v (as floats): m2 = u^2+v^2 == 2 mod 8 is never
// a perfect even square, boundary gap >= 1/(4k) ~ 6.9e-4 >> 1ulp sqrt err.
__device__ __forceinline__ int rbin_odd(float u, float v) {
    return (int)(sqrtf(fmaf(u, u, v*v)) * 0.5f);
}

__device__ __forceinline__ void cmul(float& xr, float& xi, float wr, float wi) {
    float r = xr*wr - xi*wi;
    xi = xr*wi + xi*wr;
    xr = r;
}

// 8-point DFT in registers, natural order (validated R2-R13).
__device__ __forceinline__ void dft8(float ar[8], float ai[8]) {
    const float C = 0.70710678118654752440f;
    float t0r=ar[0]+ar[4], t0i=ai[0]+ai[4];
    float t1r=ar[0]-ar[4], t1i=ai[0]-ai[4];
    float t2r=ar[2]+ar[6], t2i=ai[2]+ai[6];
    float t3r=ar[2]-ar[6], t3i=ai[2]-ai[6];
    float E0r=t0r+t2r, E0i=t0i+t2i;
    float E2r=t0r-t2r, E2i=t0i-t2i;
    float E1r=t1r+t3i, E1i=t1i-t3r;
    float E3r=t1r-t3i, E3i=t1i+t3r;
    float u0r=ar[1]+ar[5], u0i=ai[1]+ai[5];
    float u1r=ar[1]-ar[5], u1i=ai[1]-ai[5];
    float u2r=ar[3]+ar[7], u2i=ai[3]+ai[7];
    float u3r=ar[3]-ar[7], u3i=ai[3]-ai[7];
    float O0r=u0r+u2r, O0i=u0i+u2i;
    float O2r=u0r-u2r, O2i=u0i-u2i;
    float O1r=u1r+u3i, O1i=u1i-u3r;
    float O3r=u1r-u3i, O3i=u1i+u3r;
    float W1r = C*(O1r+O1i), W1i = C*(O1i-O1r);
    float W2r = O2i,         W2i = -O2r;
    float W3r = C*(O3i-O3r), W3i = -C*(O3r+O3i);
    ar[0]=E0r+O0r; ai[0]=E0i+O0i;
    ar[4]=E0r-O0r; ai[4]=E0i-O0i;
    ar[1]=E1r+W1r; ai[1]=E1i+W1i;
    ar[5]=E1r-W1r; ai[5]=E1i-W1i;
    ar[2]=E2r+W2r; ai[2]=E2i+W2i;
    ar[6]=E2r-W2r; ai[6]=E2i-W2i;
    ar[3]=E3r+W3r; ai[3]=E3i+W3i;
    ar[7]=E3r-W3r; ai[7]=E3i-W3i;
}

__device__ __forceinline__ void twiddle7(float ar[8], float ai[8], float wr, float wi) {
    float pr = wr, pi = wi;
    cmul(ar[1], ai[1], pr, pi);
    #pragma unroll
    for (int k = 2; k < 8; ++k) {
        float nr = pr*wr - pi*wi;
        pi = pr*wi + pi*wr;
        pr = nr;
        cmul(ar[k], ai[k], pr, pi);
    }
}

// TWO interleaved 512-pt FFTs through one per-wave scratch (validated R7-R13).
__device__ __forceinline__ void fft512x2(float Ar[8], float Ai[8],
                                         float Br[8], float Bi[8],
                                         float* Lr, float* Li, int lane) {
    float s1, c1, s2, c2;
    int k1 = lane >> 3, b = lane & 7;
    __sincosf((float)lane * (-6.28318530717958647692f/512.0f), &s1, &c1);
    __sincosf((float)b    * (-6.28318530717958647692f/64.0f),  &s2, &c2);
    dft8(Ar, Ai); twiddle7(Ar, Ai, c1, s1);
    dft8(Br, Bi); twiddle7(Br, Bi, c1, s1);
    #pragma unroll
    for (int j = 0; j < 8; ++j) { Lr[j*68+lane] = Ar[j]; Li[j*68+lane] = Ai[j]; }
    #pragma unroll
    for (int a = 0; a < 8; ++a) { Ar[a] = Lr[k1*68+8*a+b]; Ai[a] = Li[k1*68+8*a+b]; }
    #pragma unroll
    for (int j = 0; j < 8; ++j) { Lr[j*68+lane] = Br[j]; Li[j*68+lane] = Bi[j]; }
    dft8(Ar, Ai); twiddle7(Ar, Ai, c2, s2);
    #pragma unroll
    for (int a = 0; a < 8; ++a) { Br[a] = Lr[k1*68+8*a+b]; Bi[a] = Li[k1*68+8*a+b]; }
    dft8(Br, Bi); twiddle7(Br, Bi, c2, s2);
    #pragma unroll
    for (int cc = 0; cc < 8; ++cc) {
        int ad = k1*68 + 8*cc + ((b + cc) & 7);
        Lr[ad] = Ar[cc]; Li[ad] = Ai[cc];
    }
    #pragma unroll
    for (int bb = 0; bb < 8; ++bb) {
        int ad = k1*68 + 8*b + ((bb + b) & 7);
        Ar[bb] = Lr[ad]; Ai[bb] = Li[ad];
    }
    #pragma unroll
    for (int cc = 0; cc < 8; ++cc) {
        int ad = k1*68 + 8*cc + ((b + cc) & 7);
        Lr[ad] = Br[cc]; Li[ad] = Bi[cc];
    }
    dft8(Ar, Ai);
    #pragma unroll
    for (int bb = 0; bb < 8; ++bb) {
        int ad = k1*68 + 8*b + ((bb + b) & 7);
        Br[bb] = Lr[ad]; Bi[bb] = Li[ad];
    }
    dft8(Br, Bi);
}

// Row stage. R14: block b handles rows {64d + qb, d=0..7} (qb = b&63) so the
// column store lands pre-transposed; warp w computes d=2w (row 128w+qb) and
// d=2w+1 (row 128w+64+qb). FFT + Hermitian split unchanged from R13.
__global__ __launch_bounds__(256, 4) void k_rowfft(const float* __restrict__ pred,
                                                   const float* __restrict__ tgt,
                                                   float* __restrict__ ws) {
    __shared__ float smem[4352];
    int t = threadIdx.x, lane = t & 63, w = t >> 6;
    int b = blockIdx.x;
    int img = b >> 6;
    int qb = b & 63;
    int rA = 128*w + qb;
    const float* pA = pred + (size_t)img*PLANE + (size_t)rA*HW;
    const float* tA = tgt  + (size_t)img*PLANE + (size_t)rA*HW;
    float arA[8], aiA[8], arB[8], aiB[8];
    #pragma unroll
    for (int j = 0; j < 8; ++j) {
        arA[j] = pA[64*j + lane];         aiA[j] = tA[64*j + lane];
        arB[j] = pA[64*HW + 64*j + lane]; aiB[j] = tA[64*HW + 64*j + lane];
    }
    float* Lr = smem + w*1088;
    float* Li = Lr + 544;
    fft512x2(arA, aiA, arB, aiB, Lr, Li, lane);
    float PrA[4], PiA[4], TrA[4], TiA[4], P256A=0.f, T256A=0.f;
    float PrB[4], PiB[4], TrB[4], TiB[4], P256B=0.f, T256B=0.f;
    #pragma unroll
    for (int d = 0; d < 8; ++d) {
        int k = (lane>>3) + ((lane&7)<<3) + (d<<6);
        Lr[k] = arA[d]; Li[k] = aiA[d];
    }
    #pragma unroll
    for (int m = 0; m < 4; ++m) {
        int kk = 64*m + lane, j2 = (512 - kk) & 511;
        float z1r = Lr[kk], z1i = Li[kk], z2r = Lr[j2], z2i = Li[j2];
        PrA[m] = 0.5f*(z1r+z2r); PiA[m] = 0.5f*(z1i-z2i);
        TrA[m] = 0.5f*(z1i+z2i); TiA[m] = 0.5f*(z2r-z1r);
    }
    if (lane == 0) { P256A = Lr[256]; T256A = Li[256]; }
    #pragma unroll
    for (int d = 0; d < 8; ++d) {
        int k = (lane>>3) + ((lane&7)<<3) + (d<<6);
        Lr[k] = arB[d]; Li[k] = aiB[d];
    }
    #pragma unroll
    for (int m = 0; m < 4; ++m) {
        int kk = 64*m + lane, j2 = (512 - kk) & 511;
        float z1r = Lr[kk], z1i = Li[kk], z2r = Lr[j2], z2i = Li[j2];
        PrB[m] = 0.5f*(z1r+z2r); PiB[m] = 0.5f*(z1i-z2i);
        TrB[m] = 0.5f*(z1i+z2i); TiB[m] = 0.5f*(z2r-z1r);
    }
    if (lane == 0) { P256B = Lr[256]; T256B = Li[256]; }

    float* tR = smem;                      // [8 d][260 cols]
    float* tI = smem + 2080;
    __syncthreads();
    #pragma unroll
    for (int m = 0; m < 4; ++m) {
        int kk = 64*m + lane;
        tR[(2*w)*260 + kk]   = PrA[m]; tR[(2*w+1)*260 + kk] = PrB[m];
        tI[(2*w)*260 + kk]   = PiA[m]; tI[(2*w+1)*260 + kk] = PiB[m];
    }
    if (lane == 0) {
        tR[(2*w)*260 + 256] = P256A; tR[(2*w+1)*260 + 256] = P256B;
        tI[(2*w)*260 + 256] = 0.f;   tI[(2*w+1)*260 + 256] = 0.f;
    }
    __syncthreads();
    // P write-out: task = (comp, col); 8 floats (d=0..7) -> one contiguous
    // 32B chunk at col*512 + qb*8 (colfft reads it back as 2x dwordx4).
    for (int idx = t; idx < 514; idx += 256) {
        int comp = idx >= 257;
        int col = comp ? (idx - 257) : idx;
        const float* Tt = comp ? tI : tR;
        float4 v0, v1;
        v0.x = Tt[        col]; v0.y = Tt[ 260 + col];
        v0.z = Tt[ 520 + col];  v0.w = Tt[ 780 + col];
        v1.x = Tt[1040 + col];  v1.y = Tt[1300 + col];
        v1.z = Tt[1560 + col];  v1.w = Tt[1820 + col];
        float* outP = ws + (size_t)(comp ? OFF_PIm : OFF_PR)
                      + (size_t)img*CPC + (size_t)col*512 + qb*8;
        *(float4*)outP = v0;
        *(float4*)(outP + 4) = v1;
    }
    __syncthreads();
    #pragma unroll
    for (int m = 0; m < 4; ++m) {
        int kk = 64*m + lane;
        tR[(2*w)*260 + kk]   = TrA[m]; tR[(2*w+1)*260 + kk] = TrB[m];
        tI[(2*w)*260 + kk]   = TiA[m]; tI[(2*w+1)*260 + kk] = TiB[m];
    }
    if (lane == 0) {
        tR[(2*w)*260 + 256] = T256A; tR[(2*w+1)*260 + 256] = T256B;
        tI[(2*w)*260 + 256] = 0.f;   tI[(2*w+1)*260 + 256] = 0.f;
    }
    __syncthreads();
    for (int idx = t; idx < 514; idx += 256) {
        int comp = idx >= 257;
        int col = comp ? (idx - 257) : idx;
        const float* Tt = comp ? tI : tR;
        float4 v0, v1;
        v0.x = Tt[        col]; v0.y = Tt[ 260 + col];
        v0.z = Tt[ 520 + col];  v0.w = Tt[ 780 + col];
        v1.x = Tt[1040 + col];  v1.y = Tt[1300 + col];
        v1.z = Tt[1560 + col];  v1.w = Tt[1820 + col];
        float* outP = ws + (size_t)(comp ? OFF_TI : OFF_TR)
                      + (size_t)img*CPC + (size_t)col*512 + qb*8;
        *(float4*)outP = v0;
        *(float4*)(outP + 4) = v1;
    }
}

// Flush helper: run-collapsed atomic pair.
__device__ __forceinline__ void flush2(float* binM, float* binD, int k,
                                       float aM, float aD) {
    atomicAdd(&binM[k], aM);
    atomicAdd(&binD[k], aD);
}

// Col stage: R14 — loads are now 8 fully-coalesced global_load_dwordx4 per
// lane (column data pre-transposed into register order by k_rowfft), replacing
// 32 stride-16B scalar loads. FFT + binning identical to R13.
__global__ __launch_bounds__(256, 4) void k_colfft(const float* __restrict__ ws,
                                                   float* __restrict__ gPM,
                                                   float* __restrict__ gPD) {
    __shared__ float smem[4352];
    __shared__ float binM[NB], binD[NB];
    int t = threadIdx.x, lane = t & 63, w = t >> 6;
    for (int j = t; j < NB; j += 256) { binM[j] = 0.f; binD[j] = 0.f; }
    __syncthreads();
    int b = blockIdx.x;
    int img = b / NG;
    int g = b - img*NG;
    int c = 4*g + w;
    if (c < NC) {
        float* Lr = smem + w*1088;
        float* Li = Lr + 544;
        size_t cb = (size_t)img*CPC + (size_t)c*512 + (size_t)(lane*8);
        const float* cPR = ws + OFF_PR  + cb;
        const float* cPI = ws + OFF_PIm + cb;
        const float* cTR = ws + OFF_TR  + cb;
        const float* cTI = ws + OFF_TI  + cb;
        float4 pr0 = *(const float4*)cPR, pr1 = *(const float4*)(cPR + 4);
        float4 pi0 = *(const float4*)cPI, pi1 = *(const float4*)(cPI + 4);
        float4 tr0 = *(const float4*)cTR, tr1 = *(const float4*)(cTR + 4);
        float4 ti0 = *(const float4*)cTI, ti1 = *(const float4*)(cTI + 4);
        float prm[8] = {pr0.x,pr0.y,pr0.z,pr0.w,pr1.x,pr1.y,pr1.z,pr1.w};
        float pim[8] = {pi0.x,pi0.y,pi0.z,pi0.w,pi1.x,pi1.y,pi1.z,pi1.w};
        float trm[8] = {tr0.x,tr0.y,tr0.z,tr0.w,tr1.x,tr1.y,tr1.z,tr1.w};
        float tim[8] = {ti0.x,ti0.y,ti0.z,ti0.w,ti1.x,ti1.y,ti1.z,ti1.w};
        fft512x2(prm, pim, trm, tim, Lr, Li, lane);
        #pragma unroll
        for (int d = 0; d < 8; ++d) {
            int ky = (lane>>3) + ((lane&7)<<3) + (d<<6);
            float sp  = prm[d]*prm[d] + pim[d]*pim[d];
            float st_ = trm[d]*trm[d] + tim[d]*tim[d];
            float diff = sp - st_;
            float er = prm[d] + 1e-8f;
            Lr[ky] = 10.0f * __logf(er*er + pim[d]*pim[d]);
            Li[ky] = diff*diff;
        }
        __builtin_amdgcn_wave_barrier();
        // ---- contiguous-pair binning: lane owns p = 4*lane .. 4*lane+3 ----
        int p0 = 4*lane;
        float4 fM = *(const float4*)(Lr + p0);        // Lr[p0+j]
        float4 fD = *(const float4*)(Li + p0);
        float4 bM = *(const float4*)(Lr + 508 - p0);  // Lr[508-p0 .. 511-p0]
        float4 bD = *(const float4*)(Li + 508 - p0);
        float eM = Lr[p0 + 4], eD = Li[p0 + 4];       // Lr[p0+4], p0+4 <= 256
        int gidx = (512 - p0) & 511;
        float gM = Lr[gidx], gD = Li[gidx];
        // main pass: s[j] = L[p] + L[511-p]
        float sM[4], sD[4];
        sM[0]=fM.x+bM.w; sM[1]=fM.y+bM.z; sM[2]=fM.z+bM.y; sM[3]=fM.w+bM.x;
        sD[0]=fD.x+bD.w; sD[1]=fD.y+bD.z; sD[2]=fD.z+bD.y; sD[3]=fD.w+bD.x;
        float v1 = (c == 256) ? 511.0f : (float)(2*c + 1);
        {
            int kp = rbin_odd((float)(2*p0 + 1), v1);
            float aM = sM[0], aD = sD[0];
            #pragma unroll
            for (int j = 1; j < 4; ++j) {
                int k = rbin_odd((float)(2*(p0 + j) + 1), v1);
                if (k == kp) { aM += sM[j]; aD += sD[j]; }
                else { flush2(binM, binD, kp, aM, aD); kp = k; aM = sM[j]; aD = sD[j]; }
            }
            flush2(binM, binD, kp, aM, aD);
        }
        if (c >= 1 && c <= 255) {
            // mirror pass: s2[j] = L[(512-p)&511] + L[p+1]
            float s2M[4], s2D[4];
            s2M[0]=gM+fM.y;   s2D[0]=gD+fD.y;
            s2M[1]=bM.w+fM.z; s2D[1]=bD.w+fD.z;
            s2M[2]=bM.z+fM.w; s2D[2]=bD.z+fD.w;
            s2M[3]=bM.y+eM;   s2D[3]=bD.y+eD;
            float v2 = (float)(2*c - 1);
            int kp = rbin_odd((float)(2*p0 + 1), v2);
            float aM = s2M[0], aD = s2D[0];
            #pragma unroll
            for (int j = 1; j < 4; ++j) {
                int k = rbin_odd((float)(2*(p0 + j) + 1), v2);
                if (k == kp) { aM += s2M[j]; aD += s2D[j]; }
                else { flush2(binM, binD, kp, aM, aD); kp = k; aM = s2M[j]; aD = s2D[j]; }
            }
            flush2(binM, binD, kp, aM, aD);
        }
    }
    __syncthreads();
    for (int j = t; j < NB; j += 256) {
        gPM[(size_t)b*NB + j] = binM[j];
        gPD[(size_t)b*NB + j] = binD[j];
    }
}

// Partial-bin reduction (R13-proven, unchanged).
__global__ __launch_bounds__(256) void k_reduce(const float* __restrict__ gPM,
                                                const float* __restrict__ gPD,
                                                float* __restrict__ rM,
                                                float* __restrict__ rD) {
    __shared__ float sm[8][33], sd2[8][33];
    int b = blockIdx.x;
    int img = b / 12, ch = b - img*12;
    int jl = threadIdx.x & 31, gs = threadIdx.x >> 5;
    int j = ch*32 + jl;
    float aM = 0.f, aD = 0.f;
    if (j < NB) {
        for (int g = gs; g < NG; g += 8) {
            aM += gPM[(size_t)(img*NG + g)*NB + j];
            aD += gPD[(size_t)(img*NG + g)*NB + j];
        }
    }
    sm[gs][jl] = aM; sd2[gs][jl] = aD;
    __syncthreads();
    if (threadIdx.x < 32 && j < NB) {
        float tM = 0.f, tD = 0.f;
        #pragma unroll
        for (int s = 0; s < 8; ++s) { tM += sm[s][jl]; tD += sd2[s][jl]; }
        rM[img*NB + j] = tM;
        rD[img*NB + j] = tD;
    }
}

// Per-image final (R13-proven, unchanged).
__global__ __launch_bounds__(512) void k_final(const float* __restrict__ rM,
                                               const float* __restrict__ rD,
                                               float* __restrict__ out) {
    __shared__ int cnt[NB];
    __shared__ float meanb[NB];
    __shared__ float dsum[NB];
    __shared__ float rmin[512], rmax[512];
    __shared__ double sred[512];
    int t = threadIdx.x, img = blockIdx.x;
    for (int j = t; j < NB; j += 512) cnt[j] = 0;
    __syncthreads();
    {   // thread handles 128 contiguous v for fixed u: q = t*128 + i
        float u = (float)(2*(t >> 1) + 1);
        int vb = (t & 1) << 7;
        int kp = rbin_odd(u, (float)(2*vb + 1));
        int acc = 4;
        for (int i = 1; i < 128; ++i) {
            int k = rbin_odd(u, (float)(2*(vb + i) + 1));
            if (k == kp) acc += 4;
            else { atomicAdd(&cnt[kp], acc); kp = k; acc = 4; }
        }
        atomicAdd(&cnt[kp], acc);
    }
    __syncthreads();
    for (int j = t; j < NB; j += 512) {
        meanb[j] = rM[img*NB + j] / (float)cnt[j];
        dsum[j]  = rD[img*NB + j];
    }
    __syncthreads();
    float vmin = INFINITY, vmax = -INFINITY;
    if (t >= 1 && t <= 360) { vmin = meanb[t]; vmax = meanb[t]; }
    rmin[t] = vmin; rmax[t] = vmax;
    __syncthreads();
    for (int s = 256; s > 0; s >>= 1) {
        if (t < s) {
            float a = rmin[t], bb = rmin[t+s];
            rmin[t] = (a != a || bb != bb) ? __int_as_float(0x7fc00000) : fminf(a, bb);
            a = rmax[t]; bb = rmax[t+s];
            rmax[t] = (a != a || bb != bb) ? __int_as_float(0x7fc00000) : fmaxf(a, bb);
        }
        __syncthreads();
    }
    float pmin = rmin[0], pmax = rmax[0];
    double part = 0.0;
    for (int k = t; k < NB; k += 512) {
        float wgt;
        if (k == NB - 1) {
            wgt = 1.0f;
        } else {
            int idx = (k == 0) ? 1 : k;
            float e = (meanb[idx] - pmin) / (pmax - pmin);
            float wv = 1.0f - e;
            if (wv != wv) wv = 0.0f;
            wv = fminf(fmaxf(wv, 0.0f), 1.0f);
            wgt = wv;
        }
        part += (double)wgt * (double)dsum[k];
    }
    sred[t] = part;
    __syncthreads();
    for (int s = 256; s > 0; s >>= 1) {
        if (t < s) sred[t] += sred[t+s];
        __syncthreads();
    }
    if (t == 0) atomicAdd(out, (float)(sred[0] / 6291456.0));
}

extern "C" void kernel_launch(void* const* d_in, const int* in_sizes, int n_in,
                              void* d_out, int out_size, void* d_ws, size_t ws_size,
                              hipStream_t stream) {
    const float* pred = (const float*)d_in[0];
    const float* tgt  = (const float*)d_in[1];
    float* ws = (float*)d_ws;
    hipMemsetAsync(d_out, 0, sizeof(float), stream);
    k_rowfft<<<NIMG*64, 256, 0, stream>>>(pred, tgt, ws);
    k_colfft<<<NPB, 256, 0, stream>>>(ws, ws + OFF_PM, ws + OFF_PD);
    k_reduce<<<NIMG*12, 256, 0, stream>>>(ws + OFF_PM, ws + OFF_PD,
                                          ws + OFF_RM, ws + OFF_RD);
    k_final<<<NIMG, 512, 0, stream>>>(ws + OFF_RM, ws + OFF_RD, (float*)d_out);
}

// Round 2
// 156.184 us; speedup vs baseline: 1.0742x; 1.0742x over previous
//
#include <hip/hip_runtime.h>
#include <math.h>

#define HW 512
#define NIMG 24              // 8*3 images per tensor
#define NB 362               // radial bins
#define PLANE (HW*HW)
#define NC 257               // spectral columns kept (0..256), Hermitian half
#define NG 65                // col-groups per image (4 cols each; cg64 ragged)
#define NPB (NIMG*NG)        // 1560 partial-bin blocks
#define CP2 133120           // floats per component per image: 65 cg * 512 * 4

// ws layout (float units) — R13 layout (proven: colfft is insensitive to load
// pattern, rowfft NEEDS the 128B-run writes):
#define OFF_PM  0                          // [NPB*NB] partial mag sums
#define OFF_PD  (NPB*NB)                   // [NPB*NB] partial d sums
#define OFF_PR  (2*NPB*NB)                 // P real, [img][cg][row][4]
#define OFF_PIm (OFF_PR + NIMG*CP2)        // P imag
#define OFF_TR  (OFF_PR + 2*NIMG*CP2)      // T real
#define OFF_TI  (OFF_PR + 3*NIMG*CP2)      // T imag
#define OFF_RM  (OFF_PR + 4*NIMG*CP2)      // [NIMG*NB] reduced mag sums
#define OFF_RD  (OFF_RM + NIMG*NB)         // [NIMG*NB] reduced d sums

// Exact bin for ODD integer u,v (as floats): m2 = u^2+v^2 == 2 mod 8 is never
// a perfect even square, boundary gap >= 1/(4k) ~ 6.9e-4 >> 1ulp sqrt err.
__device__ __forceinline__ int rbin_odd(float u, float v) {
    return (int)(sqrtf(fmaf(u, u, v*v)) * 0.5f);
}

__device__ __forceinline__ void cmul(float& xr, float& xi, float wr, float wi) {
    float r = xr*wr - xi*wi;
    xi = xr*wi + xi*wr;
    xr = r;
}

// 8-point DFT in registers, natural order (validated R2-R13).
__device__ __forceinline__ void dft8(float ar[8], float ai[8]) {
    const float C = 0.70710678118654752440f;
    float t0r=ar[0]+ar[4], t0i=ai[0]+ai[4];
    float t1r=ar[0]-ar[4], t1i=ai[0]-ai[4];
    float t2r=ar[2]+ar[6], t2i=ai[2]+ai[6];
    float t3r=ar[2]-ar[6], t3i=ai[2]-ai[6];
    float E0r=t0r+t2r, E0i=t0i+t2i;
    float E2r=t0r-t2r, E2i=t0i-t2i;
    float E1r=t1r+t3i, E1i=t1i-t3r;
    float E3r=t1r-t3i, E3i=t1i+t3r;
    float u0r=ar[1]+ar[5], u0i=ai[1]+ai[5];
    float u1r=ar[1]-ar[5], u1i=ai[1]-ai[5];
    float u2r=ar[3]+ar[7], u2i=ai[3]+ai[7];
    float u3r=ar[3]-ar[7], u3i=ai[3]-ai[7];
    float O0r=u0r+u2r, O0i=u0i+u2i;
    float O2r=u0r-u2r, O2i=u0i-u2i;
    float O1r=u1r+u3i, O1i=u1i-u3r;
    float O3r=u1r-u3i, O3i=u1i+u3r;
    float W1r = C*(O1r+O1i), W1i = C*(O1i-O1r);
    float W2r = O2i,         W2i = -O2r;
    float W3r = C*(O3i-O3r), W3i = -C*(O3r+O3i);
    ar[0]=E0r+O0r; ai[0]=E0i+O0i;
    ar[4]=E0r-O0r; ai[4]=E0i-O0i;
    ar[1]=E1r+W1r; ai[1]=E1i+W1i;
    ar[5]=E1r-W1r; ai[5]=E1i-W1i;
    ar[2]=E2r+W2r; ai[2]=E2i+W2i;
    ar[6]=E2r-W2r; ai[6]=E2i-W2i;
    ar[3]=E3r+W3r; ai[3]=E3i+W3i;
    ar[7]=E3r-W3r; ai[7]=E3i-W3i;
}

__device__ __forceinline__ void twiddle7(float ar[8], float ai[8], float wr, float wi) {
    float pr = wr, pi = wi;
    cmul(ar[1], ai[1], pr, pi);
    #pragma unroll
    for (int k = 2; k < 8; ++k) {
        float nr = pr*wr - pi*wi;
        pi = pr*wi + pi*wr;
        pr = nr;
        cmul(ar[k], ai[k], pr, pi);
    }
}

// TWO interleaved 512-pt FFTs through one per-wave scratch. R15: scratch is
// float2 (re,im fused) -> ds_*_b64, HALVING the LDS instruction count of every
// transpose phase. Dataflow identical to the validated R7-R13 version.
__device__ __forceinline__ void fft512x2(float Ar[8], float Ai[8],
                                         float Br[8], float Bi[8],
                                         float2* LC, int lane) {
    float s1, c1, s2, c2;
    int k1 = lane >> 3, b = lane & 7;
    __sincosf((float)lane * (-6.28318530717958647692f/512.0f), &s1, &c1);
    __sincosf((float)b    * (-6.28318530717958647692f/64.0f),  &s2, &c2);
    dft8(Ar, Ai); twiddle7(Ar, Ai, c1, s1);
    dft8(Br, Bi); twiddle7(Br, Bi, c1, s1);
    #pragma unroll
    for (int j = 0; j < 8; ++j) LC[j*68+lane] = make_float2(Ar[j], Ai[j]);
    #pragma unroll
    for (int a = 0; a < 8; ++a) {
        float2 v = LC[k1*68+8*a+b]; Ar[a] = v.x; Ai[a] = v.y;
    }
    #pragma unroll
    for (int j = 0; j < 8; ++j) LC[j*68+lane] = make_float2(Br[j], Bi[j]);
    dft8(Ar, Ai); twiddle7(Ar, Ai, c2, s2);
    #pragma unroll
    for (int a = 0; a < 8; ++a) {
        float2 v = LC[k1*68+8*a+b]; Br[a] = v.x; Bi[a] = v.y;
    }
    dft8(Br, Bi); twiddle7(Br, Bi, c2, s2);
    #pragma unroll
    for (int cc = 0; cc < 8; ++cc) {
        int ad = k1*68 + 8*cc + ((b + cc) & 7);
        LC[ad] = make_float2(Ar[cc], Ai[cc]);
    }
    #pragma unroll
    for (int bb = 0; bb < 8; ++bb) {
        int ad = k1*68 + 8*b + ((bb + b) & 7);
        float2 v = LC[ad]; Ar[bb] = v.x; Ai[bb] = v.y;
    }
    #pragma unroll
    for (int cc = 0; cc < 8; ++cc) {
        int ad = k1*68 + 8*cc + ((b + cc) & 7);
        LC[ad] = make_float2(Br[cc], Bi[cc]);
    }
    dft8(Ar, Ai);
    #pragma unroll
    for (int bb = 0; bb < 8; ++bb) {
        int ad = k1*68 + 8*b + ((bb + b) & 7);
        float2 v = LC[ad]; Br[bb] = v.x; Bi[bb] = v.y;
    }
    dft8(Br, Bi);
}

// Row stage (R13 structure + b64-fused scratch and Hermitian split).
__global__ __launch_bounds__(256, 4) void k_rowfft(const float* __restrict__ pred,
                                                   const float* __restrict__ tgt,
                                                   float* __restrict__ ws) {
    __shared__ float2 smem2[2176];         // 4 warps * 544 float2 = 17408 B
    float* smem = (float*)smem2;
    int t = threadIdx.x, lane = t & 63, w = t >> 6;
    int b = blockIdx.x;
    int img = b >> 6;
    int r0 = (b & 63) << 3;
    int rA = r0 + 2*w;
    const float* pA = pred + (size_t)img*PLANE + (size_t)rA*HW;
    const float* tA = tgt  + (size_t)img*PLANE + (size_t)rA*HW;
    float arA[8], aiA[8], arB[8], aiB[8];
    #pragma unroll
    for (int j = 0; j < 8; ++j) {
        arA[j] = pA[64*j + lane];      aiA[j] = tA[64*j + lane];
        arB[j] = pA[HW + 64*j + lane]; aiB[j] = tA[HW + 64*j + lane];
    }
    float2* LC = smem2 + w*544;
    fft512x2(arA, aiA, arB, aiB, LC, lane);
    float PrA[4], PiA[4], TrA[4], TiA[4], P256A=0.f, T256A=0.f;
    float PrB[4], PiB[4], TrB[4], TiB[4], P256B=0.f, T256B=0.f;
    #pragma unroll
    for (int d = 0; d < 8; ++d) {
        int k = (lane>>3) + ((lane&7)<<3) + (d<<6);
        LC[k] = make_float2(arA[d], aiA[d]);
    }
    #pragma unroll
    for (int m = 0; m < 4; ++m) {
        int kk = 64*m + lane, j2 = (512 - kk) & 511;
        float2 z1 = LC[kk], z2 = LC[j2];
        PrA[m] = 0.5f*(z1.x+z2.x); PiA[m] = 0.5f*(z1.y-z2.y);
        TrA[m] = 0.5f*(z1.y+z2.y); TiA[m] = 0.5f*(z2.x-z1.x);
    }
    if (lane == 0) { float2 z = LC[256]; P256A = z.x; T256A = z.y; }
    #pragma unroll
    for (int d = 0; d < 8; ++d) {
        int k = (lane>>3) + ((lane&7)<<3) + (d<<6);
        LC[k] = make_float2(arB[d], aiB[d]);
    }
    #pragma unroll
    for (int m = 0; m < 4; ++m) {
        int kk = 64*m + lane, j2 = (512 - kk) & 511;
        float2 z1 = LC[kk], z2 = LC[j2];
        PrB[m] = 0.5f*(z1.x+z2.x); PiB[m] = 0.5f*(z1.y-z2.y);
        TrB[m] = 0.5f*(z1.y+z2.y); TiB[m] = 0.5f*(z2.x-z1.x);
    }
    if (lane == 0) { float2 z = LC[256]; P256B = z.x; T256B = z.y; }

    float* tR = smem;                      // [8][260]
    float* tI = smem + 2080;
    __syncthreads();
    #pragma unroll
    for (int m = 0; m < 4; ++m) {
        int kk = 64*m + lane;
        tR[(2*w)*260 + kk]   = PrA[m]; tR[(2*w+1)*260 + kk] = PrB[m];
        tI[(2*w)*260 + kk]   = PiA[m]; tI[(2*w+1)*260 + kk] = PiB[m];
    }
    if (lane == 0) {
        tR[(2*w)*260 + 256] = P256A; tR[(2*w+1)*260 + 256] = P256B;
        tI[(2*w)*260 + 256] = 0.f;   tI[(2*w+1)*260 + 256] = 0.f;
    }
    __syncthreads();
    for (int idx = t; idx < 1040; idx += 256) {
        int comp = idx >= 520;
        int q = idx - (comp ? 520 : 0);
        int cg = q >> 3, rl = q & 7;
        const float* Tt = comp ? tI : tR;
        float4 v = *(const float4*)(Tt + rl*260 + 4*cg);
        float* outP = ws + (size_t)(comp ? OFF_PIm : OFF_PR)
                      + (size_t)img*CP2 + cg*2048 + (r0 + rl)*4;
        *(float4*)outP = v;
    }
    __syncthreads();
    #pragma unroll
    for (int m = 0; m < 4; ++m) {
        int kk = 64*m + lane;
        tR[(2*w)*260 + kk]   = TrA[m]; tR[(2*w+1)*260 + kk] = TrB[m];
        tI[(2*w)*260 + kk]   = TiA[m]; tI[(2*w+1)*260 + kk] = TiB[m];
    }
    if (lane == 0) {
        tR[(2*w)*260 + 256] = T256A; tR[(2*w+1)*260 + 256] = T256B;
        tI[(2*w)*260 + 256] = 0.f;   tI[(2*w+1)*260 + 256] = 0.f;
    }
    __syncthreads();
    for (int idx = t; idx < 1040; idx += 256) {
        int comp = idx >= 520;
        int q = idx - (comp ? 520 : 0);
        int cg = q >> 3, rl = q & 7;
        const float* Tt = comp ? tI : tR;
        float4 v = *(const float4*)(Tt + rl*260 + 4*cg);
        float* outP = ws + (size_t)(comp ? OFF_TI : OFF_TR)
                      + (size_t)img*CP2 + cg*2048 + (r0 + rl)*4;
        *(float4*)outP = v;
    }
}

// Flush helper: run-collapsed atomic pair.
__device__ __forceinline__ void flush2(float* binM, float* binD, int k,
                                       float aM, float aD) {
    atomicAdd(&binM[k], aM);
    atomicAdd(&binD[k], aD);
}

// Col stage: R13 structure/loads + b64-fused scratch; binning staging fused as
// (logmag, d2) pairs -> ds_write_b64, pair loads via float4 on float2[].
__global__ __launch_bounds__(256, 4) void k_colfft(const float* __restrict__ ws,
                                                   float* __restrict__ gPM,
                                                   float* __restrict__ gPD) {
    __shared__ float2 smem2[2176];
    __shared__ float binM[NB], binD[NB];
    int t = threadIdx.x, lane = t & 63, w = t >> 6;
    for (int j = t; j < NB; j += 256) { binM[j] = 0.f; binD[j] = 0.f; }
    __syncthreads();
    int b = blockIdx.x;
    int img = b / NG;
    int g = b - img*NG;
    int c = 4*g + w;
    if (c < NC) {
        float2* LC = smem2 + w*544;
        float prm[8], pim[8], trm[8], tim[8];
        size_t cbase = (size_t)img*CP2 + (size_t)(c >> 2)*2048 + (c & 3);
        const float* cPR = ws + OFF_PR  + cbase;
        const float* cPI = ws + OFF_PIm + cbase;
        const float* cTR = ws + OFF_TR  + cbase;
        const float* cTI = ws + OFF_TI  + cbase;
        #pragma unroll
        for (int j = 0; j < 8; ++j) {
            int o = (64*j + lane) << 2;
            prm[j] = cPR[o]; pim[j] = cPI[o];
            trm[j] = cTR[o]; tim[j] = cTI[o];
        }
        fft512x2(prm, pim, trm, tim, LC, lane);
        #pragma unroll
        for (int d = 0; d < 8; ++d) {
            int ky = (lane>>3) + ((lane&7)<<3) + (d<<6);
            float sp  = prm[d]*prm[d] + pim[d]*pim[d];
            float st_ = trm[d]*trm[d] + tim[d]*tim[d];
            float diff = sp - st_;
            float er = prm[d] + 1e-8f;
            LC[ky] = make_float2(10.0f * __logf(er*er + pim[d]*pim[d]), diff*diff);
        }
        __builtin_amdgcn_wave_barrier();
        // ---- contiguous-pair binning: lane owns p = 4*lane .. 4*lane+3 ----
        int p0 = 4*lane;
        float4 q0  = *(const float4*)(LC + p0);        // m[p0],d[p0],m[p0+1],d[p0+1]
        float4 q1  = *(const float4*)(LC + p0 + 2);    // p0+2, p0+3
        float4 r0v = *(const float4*)(LC + (508 - p0)); // 508-p0, 509-p0
        float4 r1v = *(const float4*)(LC + (510 - p0)); // 510-p0, 511-p0
        float2 e2 = LC[p0 + 4];                        // p0+4 <= 256
        float2 g2 = LC[(512 - p0) & 511];
        // main pass: s[j] = L[p0+j] + L[511-(p0+j)]
        float sM[4], sD[4];
        sM[0]=q0.x+r1v.z; sM[1]=q0.z+r1v.x; sM[2]=q1.x+r0v.z; sM[3]=q1.z+r0v.x;
        sD[0]=q0.y+r1v.w; sD[1]=q0.w+r1v.y; sD[2]=q1.y+r0v.w; sD[3]=q1.w+r0v.y;
        float v1 = (c == 256) ? 511.0f : (float)(2*c + 1);
        {
            int kp = rbin_odd((float)(2*p0 + 1), v1);
            float aM = sM[0], aD = sD[0];
            #pragma unroll
            for (int j = 1; j < 4; ++j) {
                int k = rbin_odd((float)(2*(p0 + j) + 1), v1);
                if (k == kp) { aM += sM[j]; aD += sD[j]; }
                else { flush2(binM, binD, kp, aM, aD); kp = k; aM = sM[j]; aD = sD[j]; }
            }
            flush2(binM, binD, kp, aM, aD);
        }
        if (c >= 1 && c <= 255) {
            // mirror pass: s2[j] = L[(512-(p0+j))&511] + L[p0+j+1]
            float s2M[4], s2D[4];
            s2M[0]=g2.x+q0.z;   s2D[0]=g2.y+q0.w;
            s2M[1]=r1v.z+q1.x;  s2D[1]=r1v.w+q1.y;
            s2M[2]=r1v.x+q1.z;  s2D[2]=r1v.y+q1.w;
            s2M[3]=r0v.z+e2.x;  s2D[3]=r0v.w+e2.y;
            float v2 = (float)(2*c - 1);
            int kp = rbin_odd((float)(2*p0 + 1), v2);
            float aM = s2M[0], aD = s2D[0];
            #pragma unroll
            for (int j = 1; j < 4; ++j) {
                int k = rbin_odd((float)(2*(p0 + j) + 1), v2);
                if (k == kp) { aM += s2M[j]; aD += s2D[j]; }
                else { flush2(binM, binD, kp, aM, aD); kp = k; aM = s2M[j]; aD = s2D[j]; }
            }
            flush2(binM, binD, kp, aM, aD);
        }
    }
    __syncthreads();
    for (int j = t; j < NB; j += 256) {
        gPM[(size_t)b*NB + j] = binM[j];
        gPD[(size_t)b*NB + j] = binD[j];
    }
}

// Partial-bin reduction (R13-proven, unchanged).
__global__ __launch_bounds__(256) void k_reduce(const float* __restrict__ gPM,
                                                const float* __restrict__ gPD,
                                                float* __restrict__ rM,
                                                float* __restrict__ rD) {
    __shared__ float sm[8][33], sd2[8][33];
    int b = blockIdx.x;
    int img = b / 12, ch = b - img*12;
    int jl = threadIdx.x & 31, gs = threadIdx.x >> 5;
    int j = ch*32 + jl;
    float aM = 0.f, aD = 0.f;
    if (j < NB) {
        for (int g = gs; g < NG; g += 8) {
            aM += gPM[(size_t)(img*NG + g)*NB + j];
            aD += gPD[(size_t)(img*NG + g)*NB + j];
        }
    }
    sm[gs][jl] = aM; sd2[gs][jl] = aD;
    __syncthreads();
    if (threadIdx.x < 32 && j < NB) {
        float tM = 0.f, tD = 0.f;
        #pragma unroll
        for (int s = 0; s < 8; ++s) { tM += sm[s][jl]; tD += sd2[s][jl]; }
        rM[img*NB + j] = tM;
        rD[img*NB + j] = tD;
    }
}

// Per-image final (R13-proven, unchanged).
__global__ __launch_bounds__(512) void k_final(const float* __restrict__ rM,
                                               const float* __restrict__ rD,
                                               float* __restrict__ out) {
    __shared__ int cnt[NB];
    __shared__ float meanb[NB];
    __shared__ float dsum[NB];
    __shared__ float rmin[512], rmax[512];
    __shared__ double sred[512];
    int t = threadIdx.x, img = blockIdx.x;
    for (int j = t; j < NB; j += 512) cnt[j] = 0;
    __syncthreads();
    {   // thread handles 128 contiguous v for fixed u: q = t*128 + i
        float u = (float)(2*(t >> 1) + 1);
        int vb = (t & 1) << 7;
        int kp = rbin_odd(u, (float)(2*vb + 1));
        int acc = 4;
        for (int i = 1; i < 128; ++i) {
            int k = rbin_odd(u, (float)(2*(vb + i) + 1));
            if (k == kp) acc += 4;
            else { atomicAdd(&cnt[kp], acc); kp = k; acc = 4; }
        }
        atomicAdd(&cnt[kp], acc);
    }
    __syncthreads();
    for (int j = t; j < NB; j += 512) {
        meanb[j] = rM[img*NB + j] / (float)cnt[j];
        dsum[j]  = rD[img*NB + j];
    }
    __syncthreads();
    float vmin = INFINITY, vmax = -INFINITY;
    if (t >= 1 && t <= 360) { vmin = meanb[t]; vmax = meanb[t]; }
    rmin[t] = vmin; rmax[t] = vmax;
    __syncthreads();
    for (int s = 256; s > 0; s >>= 1) {
        if (t < s) {
            float a = rmin[t], bb = rmin[t+s];
            rmin[t] = (a != a || bb != bb) ? __int_as_float(0x7fc00000) : fminf(a, bb);
            a = rmax[t]; bb = rmax[t+s];
            rmax[t] = (a != a || bb != bb) ? __int_as_float(0x7fc00000) : fmaxf(a, bb);
        }
        __syncthreads();
    }
    float pmin = rmin[0], pmax = rmax[0];
    double part = 0.0;
    for (int k = t; k < NB; k += 512) {
        float wgt;
        if (k == NB - 1) {
            wgt = 1.0f;
        } else {
            int idx = (k == 0) ? 1 : k;
            float e = (meanb[idx] - pmin) / (pmax - pmin);
            float wv = 1.0f - e;
            if (wv != wv) wv = 0.0f;
            wv = fminf(fmaxf(wv, 0.0f), 1.0f);
            wgt = wv;
        }
        part += (double)wgt * (double)dsum[k];
    }
    sred[t] = part;
    __syncthreads();
    for (int s = 256; s > 0; s >>= 1) {
        if (t < s) sred[t] += sred[t+s];
        __syncthreads();
    }
    if (t == 0) atomicAdd(out, (float)(sred[0] / 6291456.0));
}

extern "C" void kernel_launch(void* const* d_in, const int* in_sizes, int n_in,
                              void* d_out, int out_size, void* d_ws, size_t ws_size,
                              hipStream_t stream) {
    const float* pred = (const float*)d_in[0];
    const float* tgt  = (const float*)d_in[1];
    float* ws = (float*)d_ws;
    hipMemsetAsync(d_out, 0, sizeof(float), stream);
    k_rowfft<<<NIMG*64, 256, 0, stream>>>(pred, tgt, ws);
    k_colfft<<<NPB, 256, 0, stream>>>(ws, ws + OFF_PM, ws + OFF_PD);
    k_reduce<<<NIMG*12, 256, 0, stream>>>(ws + OFF_PM, ws + OFF_PD,
                                          ws + OFF_RM, ws + OFF_RD);
    k_final<<<NIMG, 512, 0, stream>>>(ws + OFF_RM, ws + OFF_RD, (float*)d_out);
}